// Round 3
// baseline (165.437 us; speedup 1.0000x reference)
//
#include <hip/hip_runtime.h>

#define NN 50000
#define NE 1600000
#define DF 128
#define NB 1250     // buckets
#define BSZ 40      // dst nodes per bucket (NB*BSZ == NN)
#define CAP 1664    // per-bucket capacity; load 1280 +/- 36 -> +10.7 sigma
#define NWGP 256    // partition chunks (blocks [0,NWGP) of K1)
#define CHKP 6250   // edges per partition chunk (256*6250 == NE)
#define NBF2 1563   // norm blocks: 32 rows each (1024 thr, float4), guarded

typedef float v2f __attribute__((ext_vector_type(2)));
typedef float v4f __attribute__((ext_vector_type(4)));
typedef unsigned int v2u __attribute__((ext_vector_type(2)));

static __device__ __forceinline__ float bflo(unsigned int u) {
    unsigned int v = u << 16; float f; __builtin_memcpy(&f, &v, 4); return f;
}
static __device__ __forceinline__ float bfhi(unsigned int u) {
    unsigned int v = u & 0xFFFF0000u; float f; __builtin_memcpy(&f, &v, 4); return f;
}
static __device__ __forceinline__ unsigned int f2bf(float f) {   // RNE, low 16 bits
    unsigned int u; __builtin_memcpy(&u, &f, 4);
    u += 0x7FFFu + ((u >> 16) & 1u);
    return u >> 16;
}
static __device__ __forceinline__ v2f bfpair(unsigned int u) {   // (lo, hi) bf16 -> f32
    v2f r; r.x = bflo(u); r.y = bfhi(u); return r;
}
// packed fp32 math (V_PK_FMA_F32: 2 FMA/issue — neutral on its own (r2) but
// kept: fewer VALU slots leaves more issue room for VMEM on the shared pipe)
static __device__ __forceinline__ v2f pk_fma(v2f a, v2f b, v2f c) {
    v2f d;
    asm("v_pk_fma_f32 %0, %1, %2, %3" : "=v"(d) : "v"(a), "v"(b), "0"(c));
    return d;
}
static __device__ __forceinline__ v2f pk_mul(v2f a, v2f b) {
    v2f d;
    asm("v_pk_mul_f32 %0, %1, %2" : "=v"(d) : "v"(a), "v"(b));
    return d;
}
static __device__ __forceinline__ v2f pk_add(v2f a, v2f b) {
    v2f d;
    asm("v_pk_add_f32 %0, %1, %2" : "=v"(d) : "v"(a), "v"(b));
    return d;
}

// Block-wide exclusive scan, 512 threads (8 waves). 2 barriers.
static __device__ __forceinline__ int block_excl_scan512(int v, int t, int* wsum8) {
    int lane = t & 63, wv = t >> 6;
    int s = v;
    #pragma unroll
    for (int off = 1; off < 64; off <<= 1) {
        int u = __shfl_up(s, off);
        if (lane >= off) s += u;
    }
    if (lane == 63) wsum8[wv] = s;
    __syncthreads();
    int add = 0;
    #pragma unroll
    for (int w = 0; w < 8; ++w) add += (w < wv) ? wsum8[w] : 0;
    __syncthreads();
    return s + add - v;      // exclusive
}

// Block-wide exclusive scan, 1024 threads (16 waves). 2 barriers.
static __device__ __forceinline__ int block_excl_scan1024(int v, int t, int* wsum16) {
    int lane = t & 63, wv = t >> 6;
    int s = v;
    #pragma unroll
    for (int off = 1; off < 64; off <<= 1) {
        int u = __shfl_up(s, off);
        if (lane >= off) s += u;
    }
    if (lane == 63) wsum16[wv] = s;
    __syncthreads();
    int add = 0;
    #pragma unroll
    for (int w = 0; w < 16; ++w) add += (w < wv) ? wsum16[w] : 0;
    __syncthreads();
    return s + add - v;      // exclusive
}

// ---------------------------------------------------------------------------
// K1 (fused, 1024 threads this round — the probe for the invisible ~60 µs):
//  partition blocks [0,NWGP): per-thread serial depth halved (6250 edges over
//    1024 threads = 6.1 iters/pass vs 12.2). Same counting-sort algorithm.
//  norm blocks: 32 rows each (32 lanes x float4 per row), guarded at NN.
//  Streaming accesses use non-temporal hints to keep L2 clean.
// ---------------------------------------------------------------------------
__global__ __launch_bounds__(1024)
void k_norm_part(const float* __restrict__ x,
                 const int* __restrict__ ei,
                 unsigned int* __restrict__ xn_bf,
                 float* __restrict__ norm,
                 unsigned int* __restrict__ descG,
                 unsigned int* __restrict__ pairs) {
    __shared__ int wsum16[16];
    __shared__ int cntL[NB];
    __shared__ int offL[NB];
    __shared__ unsigned int stg[CHKP];          // 25 KB
    int t = threadIdx.x;
    if (blockIdx.x >= NWGP) {
        int l32 = t & 31;
        int node = (blockIdx.x - NWGP) * 32 + (t >> 5);
        if (node < NN) {
            v4f v = __builtin_nontemporal_load(((const v4f*)(x + (size_t)node * DF)) + l32);
            float ss = v.x * v.x + v.y * v.y + v.z * v.z + v.w * v.w;
            #pragma unroll
            for (int m = 1; m < 32; m <<= 1) ss += __shfl_xor(ss, m);  // 32-lane group
            float rinv = rsqrtf(fmaxf(ss, 1e-24f));
            v2u p;
            p.x = (f2bf(v.y * rinv) << 16) | f2bf(v.x * rinv);
            p.y = (f2bf(v.w * rinv) << 16) | f2bf(v.z * rinv);
            ((v2u*)(xn_bf + (size_t)node * 64))[l32] = p;    // reused by K2: default
            if (l32 == 0) norm[node] = ss * rinv;            // == ||x||, smooth at 0
        }
        return;
    }
    int wg = blockIdx.x;
    const int* srcp = ei + wg * CHKP;
    const int* dstp = ei + NE + wg * CHKP;
    for (int i = t; i < NB; i += 1024) cntL[i] = 0;
    __syncthreads();
    #pragma unroll 4
    for (int i = t; i < CHKP; i += 1024) atomicAdd(&cntL[dstp[i] / BSZ], 1);
    __syncthreads();
    {   // exclusive scan of cntL[0..NB): 2 consecutive values per thread
        int base = t * 2;
        int loc[2];
        int s = 0;
        #pragma unroll
        for (int q = 0; q < 2; ++q) {
            int idx = base + q;
            int v = (idx < NB) ? cntL[idx] : 0;
            loc[q] = s;
            s += v;
        }
        int ex = block_excl_scan1024(s, t, wsum16);
        #pragma unroll
        for (int q = 0; q < 2; ++q) {
            int idx = base + q;
            if (idx < NB) offL[idx] = ex + loc[q];
        }
    }
    __syncthreads();
    // packed descriptor row, coalesced (off,cnt <= 6250 both fit 16 bits)
    for (int i = t; i < NB; i += 1024)
        __builtin_nontemporal_store(((unsigned int)offL[i] << 16) | (unsigned int)cntL[i],
                                    &descG[(size_t)wg * NB + i]);
    __syncthreads();                 // all offL reads done before cursor bumps
    #pragma unroll 2
    for (int i = t; i < CHKP; i += 1024) {
        int src = __builtin_nontemporal_load(&srcp[i]);   // read once
        int dst = dstp[i];                                // 2nd read: L2-resident
        int b = dst / BSZ;
        int pos = atomicAdd(&offL[b], 1);
        stg[pos] = ((unsigned int)(dst - b * BSZ) << 16) | (unsigned int)src;
    }
    __syncthreads();
    unsigned int* chunk = pairs + (size_t)wg * CHKP;
    #pragma unroll 4
    for (int i = t; i < CHKP; i += 1024)
        __builtin_nontemporal_store(stg[i], &chunk[i]);
}

// ---------------------------------------------------------------------------
// K2 (fused build + gather): one block (512 thr, 8 waves) per bucket.
//  Compute structure FROZEN from r2 (control). This round only: non-temporal
//  hints on streaming traffic (descG/pairs loads, out stores) so the 4 MB
//  per-XCD L2 is reserved for the xn_bf row gather — the identified
//  beyond-L2-path bottleneck (~2.4 TB/s effective, FETCH 177 MB invariant).
// ---------------------------------------------------------------------------
__global__ __launch_bounds__(512)
void k_build_gather(const unsigned int* __restrict__ xn_bf,
                    const float* __restrict__ norm,
                    const unsigned int* __restrict__ descG,
                    const unsigned int* __restrict__ pairs,
                    const float* __restrict__ beta_p,
                    float* __restrict__ out) {
    __shared__ int wsum8[8];
    __shared__ int lenS[NWGP], offS[NWGP], rbase[NWGP];
    __shared__ unsigned int rawL[CAP];
    __shared__ unsigned int colL[CAP];
    __shared__ int hist[BSZ];
    __shared__ int rp[BSZ + 1];
    __shared__ int stot;
    int b = blockIdx.x, t = threadIdx.x;

    {   // desc read (one per thread for t<256) + 512-wide block scan
        unsigned int d = (t < NWGP) ? __builtin_nontemporal_load(&descG[(size_t)t * NB + b]) : 0u;
        int len = (int)(d & 0xFFFFu);
        int ex = block_excl_scan512(len, t, wsum8);
        if (t < NWGP) {
            lenS[t] = len;
            offS[t] = (int)(d >> 16);
            rbase[t] = ex;
        }
        if (t == NWGP - 1) stot = ex + len;
    }
    if (t < BSZ) hist[t] = 0;
    __syncthreads();
    int cnt = stot;
    if (cnt > CAP) cnt = CAP;        // never fires (memory safety)

    // cooperative run copy: 64 groups x 8 lanes over 256 runs (4 iterations)
    int g8 = t >> 3, l8 = t & 7;
    for (int r = g8; r < NWGP; r += 64) {
        int len = lenS[r];
        int rb = rbase[r];
        const unsigned int* sp = pairs + (size_t)r * CHKP + offS[r];
        for (int q = l8; q < len; q += 8) {
            int pos = rb + q;
            if (pos < CAP) rawL[pos] = __builtin_nontemporal_load(&sp[q]);
        }
    }
    __syncthreads();
    for (int i = t; i < cnt; i += 512) atomicAdd(&hist[rawL[i] >> 16], 1);
    __syncthreads();
    if (t < 64) {                    // single-wave scan (BSZ=40 < 64)
        int v = (t < BSZ) ? hist[t] : 0;
        int s = v;
        #pragma unroll
        for (int off = 1; off < 64; off <<= 1) {
            int u = __shfl_up(s, off);
            if (t >= off) s += u;
        }
        if (t < BSZ) { rp[t + 1] = s; hist[t] = s - v; }   // cursor = exclusive
        if (t == 0) rp[0] = 0;
    }
    __syncthreads();
    for (int i = t; i < cnt; i += 512) {
        unsigned int p = rawL[i];
        unsigned int src = p & 0xFFFFu;
        int pos = atomicAdd(&hist[p >> 16], 1);
        colL[pos] = (f2bf(norm[src]) << 16) | src;
    }
    __syncthreads();

    // ---- gather (col/rp from LDS) ----
    int lane = t & 63;
    int w = t >> 6;                  // 8 waves
    int j = lane & 15;
    int g = lane >> 4;
    float beta = beta_p[0];
    float c = -fabsf(beta);
    for (int ln = w; ln < BSZ; ln += 8) {
        int node = b * BSZ + ln;
        uint4 du = ((const uint4*)(xn_bf + (size_t)node * 64))[j];
        v2f xd2[4];
        #pragma unroll
        for (int q = 0; q < 4; ++q) xd2[q] = bfpair((&du.x)[q]);
        v2f acc2[4];
        #pragma unroll
        for (int q = 0; q < 4; ++q) { acc2[q].x = 0.f; acc2[q].y = 0.f; }
        float ssum = 0.f;
        int b0 = rp[ln], b1 = rp[ln + 1];

        int k = b0 + g;
        int kA = (k     < b1) ? k     : 0;
        int kB = (k + 4 < b1) ? k + 4 : 0;
        unsigned int pA = colL[kA];
        unsigned int pB = colL[kB];
        uint4 rA = ((const uint4*)(xn_bf + (size_t)(pA & 0xFFFFu) * 64))[j];
        uint4 rB = ((const uint4*)(xn_bf + (size_t)(pB & 0xFFFFu) * 64))[j];

        for (; k < b1; k += 8) {
            int kC = (k +  8 < b1) ? k +  8 : 0;
            int kD = (k + 12 < b1) ? k + 12 : 0;
            unsigned int pC = colL[kC];
            unsigned int pD = colL[kD];
            uint4 rC = ((const uint4*)(xn_bf + (size_t)(pC & 0xFFFFu) * 64))[j];
            uint4 rD = ((const uint4*)(xn_bf + (size_t)(pD & 0xFFFFu) * 64))[j];

            // unpack both edges' rows to f32 pairs
            v2f xsA[4], xsB[4];
            #pragma unroll
            for (int q = 0; q < 4; ++q) {
                xsA[q] = bfpair((&rA.x)[q]);
                xsB[q] = bfpair((&rB.x)[q]);
            }
            // packed dots: dpA/.x holds evens, .y holds odds
            v2f dpA = pk_mul(xd2[0], xsA[0]);
            v2f dpB = pk_mul(xd2[0], xsB[0]);
            #pragma unroll
            for (int q = 1; q < 4; ++q) {
                dpA = pk_fma(xd2[q], xsA[q], dpA);
                dpB = pk_fma(xd2[q], xsB[q], dpB);
            }
            // pack (dotA, dotB) and reduce across the 16-lane group
            v2f dAB;
            dAB.x = dpA.x + dpA.y;
            dAB.y = dpB.x + dpB.y;
            #pragma unroll
            for (int m = 1; m < 16; m <<= 1) {
                v2f o;
                o.x = __shfl_xor(dAB.x, m);
                o.y = __shfl_xor(dAB.y, m);
                dAB = pk_add(dAB, o);
            }
            float eA = __expf(fmaf(beta, dAB.x, c));
            float eB = __expf(fmaf(beta, dAB.y, c));
            eB = (k + 4 < b1) ? eB : 0.f;
            ssum += eA + eB;
            float wA = eA * bfhi(pA);
            float wB = eB * bfhi(pB);
            v2f wA2; wA2.x = wA; wA2.y = wA;
            v2f wB2; wB2.x = wB; wB2.y = wB;
            #pragma unroll
            for (int q = 0; q < 4; ++q) {
                acc2[q] = pk_fma(wA2, xsA[q], acc2[q]);
                acc2[q] = pk_fma(wB2, xsB[q], acc2[q]);
            }
            pA = pC; pB = pD; rA = rC; rB = rD;
        }

        ssum += __shfl_xor(ssum, 16);
        ssum += __shfl_xor(ssum, 32);
        #pragma unroll
        for (int q = 0; q < 4; ++q) {
            v2f o;
            o.x = __shfl_xor(acc2[q].x, 16);
            o.y = __shfl_xor(acc2[q].y, 16);
            acc2[q] = pk_add(acc2[q], o);
            o.x = __shfl_xor(acc2[q].x, 32);
            o.y = __shfl_xor(acc2[q].y, 32);
            acc2[q] = pk_add(acc2[q], o);
        }
        float e_self = __expf(beta + c);          // self-loop, cos = 1
        ssum += e_self;
        float wsl = e_self * norm[node];
        v2f wsl2; wsl2.x = wsl; wsl2.y = wsl;
        #pragma unroll
        for (int q = 0; q < 4; ++q) acc2[q] = pk_fma(wsl2, xd2[q], acc2[q]);

        if (g == 0) {
            float inv = 1.0f / ssum;
            v4f o0, o1;
            o0.x = fmaxf(0.f, acc2[0].x * inv); o0.y = fmaxf(0.f, acc2[0].y * inv);
            o0.z = fmaxf(0.f, acc2[1].x * inv); o0.w = fmaxf(0.f, acc2[1].y * inv);
            o1.x = fmaxf(0.f, acc2[2].x * inv); o1.y = fmaxf(0.f, acc2[2].y * inv);
            o1.z = fmaxf(0.f, acc2[3].x * inv); o1.w = fmaxf(0.f, acc2[3].y * inv);
            v4f* op = (v4f*)(out + (size_t)node * DF + 8 * j);
            __builtin_nontemporal_store(o0, op);
            __builtin_nontemporal_store(o1, op + 1);
        }
    }
}

extern "C" void kernel_launch(void* const* d_in, const int* in_sizes, int n_in,
                              void* d_out, int out_size, void* d_ws, size_t ws_size,
                              hipStream_t stream) {
    const float* x    = (const float*)d_in[0];   // fp32 [NN*DF]
    const float* beta = (const float*)d_in[1];   // fp32 [1]
    const int*   ei   = (const int*)d_in[2];     // int32 [2*NE]
    float*       out  = (float*)d_out;           // fp32 [NN*DF]

    // workspace layout (bytes), total ~20.7 MiB:
    char* ws = (char*)d_ws;
    unsigned int* xn_bf = (unsigned int*)ws;                  // NN*64*4 = 12,800,000
    float* norm = (float*)(ws + 12800000);                    // NN*4    =    200,000
    unsigned int* descG = (unsigned int*)(ws + 13000000);     // NWGP*NB*4 = 1,280,000
    unsigned int* pairs = (unsigned int*)(ws + 14280000);     // NE*4 = 6,400,000

    k_norm_part  <<<NWGP + NBF2, 1024, 0, stream>>>(x, ei, xn_bf, norm, descG, pairs);
    k_build_gather<<<NB,         512,  0, stream>>>(xn_bf, norm, descG, pairs, beta, out);
}

// Round 4
// 155.922 us; speedup vs baseline: 1.0610x; 1.0610x over previous
//
#include <hip/hip_runtime.h>

#define NN 50000
#define NE 1600000
#define DF 128
#define NB 1250     // buckets
#define BSZ 40      // dst nodes per bucket (NB*BSZ == NN)
#define CAP 1664    // per-bucket capacity; load 1280 +/- 36 -> +10.7 sigma
#define NWGP 256    // partition chunks (blocks [0,NWGP) of K1)
#define CHKP 6250   // edges per partition chunk (256*6250 == NE)
#define NBF 3125    // norm blocks: 16 rows each (512 thr, float4)

typedef float v2f __attribute__((ext_vector_type(2)));
typedef float v4f __attribute__((ext_vector_type(4)));
typedef unsigned int v2u __attribute__((ext_vector_type(2)));

static __device__ __forceinline__ float bflo(unsigned int u) {
    unsigned int v = u << 16; float f; __builtin_memcpy(&f, &v, 4); return f;
}
static __device__ __forceinline__ float bfhi(unsigned int u) {
    unsigned int v = u & 0xFFFF0000u; float f; __builtin_memcpy(&f, &v, 4); return f;
}
static __device__ __forceinline__ unsigned int f2bf(float f) {   // RNE, low 16 bits
    unsigned int u; __builtin_memcpy(&u, &f, 4);
    u += 0x7FFFu + ((u >> 16) & 1u);
    return u >> 16;
}
// unpack 4 signed int8 packed in a u32 -> 4 floats (bfe_i32 + cvt each)
static __device__ __forceinline__ v4f cvt4_i8(unsigned int u) {
    v4f r;
    r.x = (float)(int)(signed char)(u);
    r.y = (float)(int)(signed char)(u >> 8);
    r.z = (float)(int)(signed char)(u >> 16);
    r.w = (float)(int)(signed char)(u >> 24);
    return r;
}
// packed fp32 math (V_PK_FMA_F32 et al.)
static __device__ __forceinline__ v2f pk_fma(v2f a, v2f b, v2f c) {
    v2f d;
    asm("v_pk_fma_f32 %0, %1, %2, %3" : "=v"(d) : "v"(a), "v"(b), "0"(c));
    return d;
}
static __device__ __forceinline__ v2f pk_mul(v2f a, v2f b) {
    v2f d;
    asm("v_pk_mul_f32 %0, %1, %2" : "=v"(d) : "v"(a), "v"(b));
    return d;
}
static __device__ __forceinline__ v2f pk_add(v2f a, v2f b) {
    v2f d;
    asm("v_pk_add_f32 %0, %1, %2" : "=v"(d) : "v"(a), "v"(b));
    return d;
}

// Block-wide exclusive scan, 512 threads (8 waves). 2 barriers.
static __device__ __forceinline__ int block_excl_scan512(int v, int t, int* wsum8) {
    int lane = t & 63, wv = t >> 6;
    int s = v;
    #pragma unroll
    for (int off = 1; off < 64; off <<= 1) {
        int u = __shfl_up(s, off);
        if (lane >= off) s += u;
    }
    if (lane == 63) wsum8[wv] = s;
    __syncthreads();
    int add = 0;
    #pragma unroll
    for (int w = 0; w < 8; ++w) add += (w < wv) ? wsum8[w] : 0;
    __syncthreads();
    return s + add - v;      // exclusive
}

// Block-wide exclusive scan, 256 threads (4 waves). 2 barriers.
static __device__ __forceinline__ int block_excl_scan256(int v, int t, int* wsum4) {
    int lane = t & 63, wv = t >> 6;
    int s = v;
    #pragma unroll
    for (int off = 1; off < 64; off <<= 1) {
        int u = __shfl_up(s, off);
        if (lane >= off) s += u;
    }
    if (lane == 63) wsum4[wv] = s;
    __syncthreads();
    int add = 0;
    #pragma unroll
    for (int w = 0; w < 4; ++w) add += (w < wv) ? wsum4[w] : 0;
    __syncthreads();
    return s + add - v;      // exclusive
}

// ---------------------------------------------------------------------------
// K1 (r0 structure: 512 thr; partition blocks [0,NWGP) then norm blocks):
//  norm: per row compute ss = |x|^2 and am = max|x_d|; store
//        xq[node] = int8 row q_d = round(127 x_d / am)  (128 B/row, 6.4 MB)
//        sn[node] = packed { hi: bf16(m = am/127), lo: bf16(s = m/|x|) }
//        norm[node] = |x|  (f32, self-loop weight)
//        Identities: x_rec = m*q; xn_rec = s*q. No bf16 row copy at all —
//        working set for K2's random gather drops 12.8 -> 6.4 MB and issued
//        gather bytes halve (256 -> 128 B/row). That is the r3-identified
//        bottleneck (L2-miss path saturated at ~2.46 TB/s, FETCH 177 MB).
//  partition: unchanged counting sort (NO non-temporal hints — r3: -4 µs).
// ---------------------------------------------------------------------------
__global__ __launch_bounds__(512)
void k_norm_part(const float* __restrict__ x,
                 const int* __restrict__ ei,
                 unsigned int* __restrict__ xq,
                 float* __restrict__ norm,
                 unsigned int* __restrict__ sn,
                 unsigned int* __restrict__ descG,
                 unsigned int* __restrict__ pairs) {
    __shared__ int wsum8[8];
    __shared__ int cntL[NB];
    __shared__ int offL[NB];
    __shared__ unsigned int stg[CHKP];          // 25 KB
    int t = threadIdx.x;
    if (blockIdx.x >= NWGP) {
        int l32 = t & 31;
        int node = (blockIdx.x - NWGP) * 16 + (t >> 5);
        float4 v = ((const float4*)(x + (size_t)node * DF))[l32];
        float ss = v.x * v.x + v.y * v.y + v.z * v.z + v.w * v.w;
        float am = fmaxf(fmaxf(fabsf(v.x), fabsf(v.y)), fmaxf(fabsf(v.z), fabsf(v.w)));
        #pragma unroll
        for (int m = 1; m < 32; m <<= 1) {
            ss += __shfl_xor(ss, m);                       // 32-lane group sum
            am = fmaxf(am, __shfl_xor(am, m));             // 32-lane group max
        }
        float rinv = rsqrtf(fmaxf(ss, 1e-24f));
        am = fmaxf(am, 1e-30f);
        float qsc = 127.0f / am;
        int q0 = (int)rintf(v.x * qsc);
        int q1 = (int)rintf(v.y * qsc);
        int q2 = (int)rintf(v.z * qsc);
        int q3 = (int)rintf(v.w * qsc);
        unsigned int u = (q0 & 255) | ((q1 & 255) << 8) | ((q2 & 255) << 16)
                       | ((unsigned int)q3 << 24);
        xq[(size_t)node * 32 + l32] = u;
        if (l32 == 0) {
            float m = am * (1.0f / 127.0f);      // weight scale: x_rec = m*q
            float s = rinv * m;                  // logit scale: xn_rec = s*q
            norm[node] = ss * rinv;              // == |x|
            sn[node] = (f2bf(m) << 16) | f2bf(s);
        }
        return;
    }
    int wg = blockIdx.x;
    const int* srcp = ei + wg * CHKP;
    const int* dstp = ei + NE + wg * CHKP;
    for (int i = t; i < NB; i += 512) cntL[i] = 0;
    __syncthreads();
    #pragma unroll 4
    for (int i = t; i < CHKP; i += 512) atomicAdd(&cntL[dstp[i] / BSZ], 1);
    __syncthreads();
    {   // exclusive scan of cntL[0..NB): 3 consecutive values per thread
        int base = t * 3;
        int loc[3];
        int s = 0;
        #pragma unroll
        for (int q = 0; q < 3; ++q) {
            int idx = base + q;
            int v = (idx < NB) ? cntL[idx] : 0;
            loc[q] = s;
            s += v;
        }
        int ex = block_excl_scan512(s, t, wsum8);
        #pragma unroll
        for (int q = 0; q < 3; ++q) {
            int idx = base + q;
            if (idx < NB) offL[idx] = ex + loc[q];
        }
    }
    __syncthreads();
    // packed descriptor row, coalesced (off,cnt <= 6250 both fit 16 bits)
    for (int i = t; i < NB; i += 512)
        descG[(size_t)wg * NB + i] = ((unsigned int)offL[i] << 16) | (unsigned int)cntL[i];
    __syncthreads();                 // all offL reads done before cursor bumps
    #pragma unroll 2
    for (int i = t; i < CHKP; i += 512) {
        int src = srcp[i];
        int dst = dstp[i];
        int b = dst / BSZ;
        int pos = atomicAdd(&offL[b], 1);
        stg[pos] = ((unsigned int)(dst - b * BSZ) << 16) | (unsigned int)src;
    }
    __syncthreads();
    unsigned int* chunk = pairs + (size_t)wg * CHKP;
    #pragma unroll 4
    for (int i = t; i < CHKP; i += 512) chunk[i] = stg[i];
}

// ---------------------------------------------------------------------------
// K2 (fused build + gather): one block (256 thr — r0's empirically best
// config; r1 showed 512-thr is -4%) per bucket. int8 rows this round:
//  gather row read = 16 lanes x uint2 (128 B), unpack via cvt4_i8.
//  Per edge: dot_q = sum(q_dst * q_src) in f32; logit = beta*s_dst*s_src*dot;
//  weight on q_src = e * m_src (m = |x|*s), i.e. acc accumulates x units.
//  Self-loop: x_dst_rec = norm*s_dst*q_dst. No NT hints (r3 regression).
// ---------------------------------------------------------------------------
__global__ __launch_bounds__(256)
void k_build_gather(const unsigned int* __restrict__ xq,
                    const unsigned int* __restrict__ sn,
                    const float* __restrict__ norm,
                    const unsigned int* __restrict__ descG,
                    const unsigned int* __restrict__ pairs,
                    const float* __restrict__ beta_p,
                    float* __restrict__ out) {
    __shared__ int wsum4[4];
    __shared__ int lenS[NWGP], offS[NWGP], rbase[NWGP];
    __shared__ unsigned int rawL[CAP];
    __shared__ unsigned int colSrc[CAP];
    __shared__ unsigned int colSN[CAP];
    __shared__ int hist[BSZ];
    __shared__ int rp[BSZ + 1];
    __shared__ int stot;
    int b = blockIdx.x, t = threadIdx.x;

    {   // desc read (one per thread, 256 runs) + block scan
        unsigned int d = descG[(size_t)t * NB + b];
        int len = (int)(d & 0xFFFFu);
        int ex = block_excl_scan256(len, t, wsum4);
        lenS[t] = len;
        offS[t] = (int)(d >> 16);
        rbase[t] = ex;
        if (t == 255) stot = ex + len;
    }
    if (t < BSZ) hist[t] = 0;
    __syncthreads();
    int cnt = stot;
    if (cnt > CAP) cnt = CAP;        // never fires (memory safety)

    // cooperative run copy: 32 groups x 8 lanes over 256 runs (8 iterations)
    int g8 = t >> 3, l8 = t & 7;
    for (int r = g8; r < NWGP; r += 32) {
        int len = lenS[r];
        int rb = rbase[r];
        const unsigned int* sp = pairs + (size_t)r * CHKP + offS[r];
        for (int q = l8; q < len; q += 8) {
            int pos = rb + q;
            if (pos < CAP) rawL[pos] = sp[q];
        }
    }
    __syncthreads();
    for (int i = t; i < cnt; i += 256) atomicAdd(&hist[rawL[i] >> 16], 1);
    __syncthreads();
    if (t < 64) {                    // single-wave scan (BSZ=40 < 64)
        int v = (t < BSZ) ? hist[t] : 0;
        int s = v;
        #pragma unroll
        for (int off = 1; off < 64; off <<= 1) {
            int u = __shfl_up(s, off);
            if (t >= off) s += u;
        }
        if (t < BSZ) { rp[t + 1] = s; hist[t] = s - v; }   // cursor = exclusive
        if (t == 0) rp[0] = 0;
    }
    __syncthreads();
    for (int i = t; i < cnt; i += 256) {
        unsigned int p = rawL[i];
        unsigned int src = p & 0xFFFFu;
        int pos = atomicAdd(&hist[p >> 16], 1);
        colSrc[pos] = src;
        colSN[pos] = sn[src];        // packed {bf16 m, bf16 s}, L2-resident
    }
    __syncthreads();

    // ---- gather (colSrc/colSN/rp from LDS) ----
    int lane = t & 63;
    int w = t >> 6;                  // 4 waves
    int j = lane & 15;
    int g = lane >> 4;
    float beta = beta_p[0];
    float c = -fabsf(beta);
    for (int ln = w; ln < BSZ; ln += 4) {
        int node = b * BSZ + ln;
        v2u du = ((const v2u*)(xq + (size_t)node * 32))[j];
        v4f c0 = cvt4_i8(du.x), c1 = cvt4_i8(du.y);
        v2f xd2[4];
        xd2[0].x = c0.x; xd2[0].y = c0.y;
        xd2[1].x = c0.z; xd2[1].y = c0.w;
        xd2[2].x = c1.x; xd2[2].y = c1.y;
        xd2[3].x = c1.z; xd2[3].y = c1.w;
        float sd = bflo(sn[node]);               // logit scale of dst
        float ke = beta * sd;
        v2f acc2[4];
        #pragma unroll
        for (int q = 0; q < 4; ++q) { acc2[q].x = 0.f; acc2[q].y = 0.f; }
        float ssum = 0.f;
        int b0 = rp[ln], b1 = rp[ln + 1];

        int k = b0 + g;
        int kA = (k     < b1) ? k     : 0;
        int kB = (k + 4 < b1) ? k + 4 : 0;
        unsigned int srcA = colSrc[kA] & 0xFFFFu;
        unsigned int srcB = colSrc[kB] & 0xFFFFu;
        unsigned int snA = colSN[kA];
        unsigned int snB = colSN[kB];
        v2u rA = ((const v2u*)(xq + (size_t)srcA * 32))[j];
        v2u rB = ((const v2u*)(xq + (size_t)srcB * 32))[j];

        for (; k < b1; k += 8) {
            int kC = (k +  8 < b1) ? k +  8 : 0;
            int kD = (k + 12 < b1) ? k + 12 : 0;
            unsigned int srcC = colSrc[kC] & 0xFFFFu;
            unsigned int srcD = colSrc[kD] & 0xFFFFu;
            unsigned int snC = colSN[kC];
            unsigned int snD = colSN[kD];
            v2u rC = ((const v2u*)(xq + (size_t)srcC * 32))[j];
            v2u rD = ((const v2u*)(xq + (size_t)srcD * 32))[j];

            // unpack both edges' int8 rows to f32 pairs
            v4f a0 = cvt4_i8(rA.x), a1 = cvt4_i8(rA.y);
            v4f b0v = cvt4_i8(rB.x), b1v = cvt4_i8(rB.y);
            v2f xsA[4], xsB[4];
            xsA[0].x = a0.x; xsA[0].y = a0.y;  xsA[1].x = a0.z; xsA[1].y = a0.w;
            xsA[2].x = a1.x; xsA[2].y = a1.y;  xsA[3].x = a1.z; xsA[3].y = a1.w;
            xsB[0].x = b0v.x; xsB[0].y = b0v.y; xsB[1].x = b0v.z; xsB[1].y = b0v.w;
            xsB[2].x = b1v.x; xsB[2].y = b1v.y; xsB[3].x = b1v.z; xsB[3].y = b1v.w;
            // packed q.q dots (|dot| <= 128*127^2 ~ 2e6, exact in f32)
            v2f dpA = pk_mul(xd2[0], xsA[0]);
            v2f dpB = pk_mul(xd2[0], xsB[0]);
            #pragma unroll
            for (int q = 1; q < 4; ++q) {
                dpA = pk_fma(xd2[q], xsA[q], dpA);
                dpB = pk_fma(xd2[q], xsB[q], dpB);
            }
            v2f dAB;
            dAB.x = dpA.x + dpA.y;
            dAB.y = dpB.x + dpB.y;
            #pragma unroll
            for (int m = 1; m < 16; m <<= 1) {
                v2f o;
                o.x = __shfl_xor(dAB.x, m);
                o.y = __shfl_xor(dAB.y, m);
                dAB = pk_add(dAB, o);
            }
            float eA = __expf(fmaf(ke * bflo(snA), dAB.x, c));
            float eB = __expf(fmaf(ke * bflo(snB), dAB.y, c));
            eB = (k + 4 < b1) ? eB : 0.f;
            ssum += eA + eB;
            float wA = eA * bfhi(snA);           // e * m_src  (x units)
            float wB = eB * bfhi(snB);
            v2f wA2; wA2.x = wA; wA2.y = wA;
            v2f wB2; wB2.x = wB; wB2.y = wB;
            #pragma unroll
            for (int q = 0; q < 4; ++q) {
                acc2[q] = pk_fma(wA2, xsA[q], acc2[q]);
                acc2[q] = pk_fma(wB2, xsB[q], acc2[q]);
            }
            srcA = srcC; srcB = srcD; snA = snC; snB = snD; rA = rC; rB = rD;
        }

        ssum += __shfl_xor(ssum, 16);
        ssum += __shfl_xor(ssum, 32);
        #pragma unroll
        for (int q = 0; q < 4; ++q) {
            v2f o;
            o.x = __shfl_xor(acc2[q].x, 16);
            o.y = __shfl_xor(acc2[q].y, 16);
            acc2[q] = pk_add(acc2[q], o);
            o.x = __shfl_xor(acc2[q].x, 32);
            o.y = __shfl_xor(acc2[q].y, 32);
            acc2[q] = pk_add(acc2[q], o);
        }
        float e_self = __expf(beta + c);          // self-loop, cos = 1 exact
        ssum += e_self;
        float wsl = e_self * norm[node] * sd;     // x_dst_rec = norm*s_dst*q
        v2f wsl2; wsl2.x = wsl; wsl2.y = wsl;
        #pragma unroll
        for (int q = 0; q < 4; ++q) acc2[q] = pk_fma(wsl2, xd2[q], acc2[q]);

        if (g == 0) {
            float inv = 1.0f / ssum;
            float4 o0, o1;
            o0.x = fmaxf(0.f, acc2[0].x * inv); o0.y = fmaxf(0.f, acc2[0].y * inv);
            o0.z = fmaxf(0.f, acc2[1].x * inv); o0.w = fmaxf(0.f, acc2[1].y * inv);
            o1.x = fmaxf(0.f, acc2[2].x * inv); o1.y = fmaxf(0.f, acc2[2].y * inv);
            o1.z = fmaxf(0.f, acc2[3].x * inv); o1.w = fmaxf(0.f, acc2[3].y * inv);
            float4* op = (float4*)(out + (size_t)node * DF + 8 * j);
            op[0] = o0;
            op[1] = o1;
        }
    }
}

extern "C" void kernel_launch(void* const* d_in, const int* in_sizes, int n_in,
                              void* d_out, int out_size, void* d_ws, size_t ws_size,
                              hipStream_t stream) {
    const float* x    = (const float*)d_in[0];   // fp32 [NN*DF]
    const float* beta = (const float*)d_in[1];   // fp32 [1]
    const int*   ei   = (const int*)d_in[2];     // int32 [2*NE]
    float*       out  = (float*)d_out;           // fp32 [NN*DF]

    // workspace layout (bytes), total ~14.5 MiB (was 20.7 — bf16 rows dropped):
    char* ws = (char*)d_ws;
    unsigned int* xq    = (unsigned int*)ws;                  // NN*128  = 6,400,000
    float*        norm  = (float*)(ws + 6400000);             // NN*4    =   200,000
    unsigned int* sn    = (unsigned int*)(ws + 6600000);      // NN*4    =   200,000
    unsigned int* descG = (unsigned int*)(ws + 6800000);      // NWGP*NB*4 = 1,280,000
    unsigned int* pairs = (unsigned int*)(ws + 8080000);      // NE*4 = 6,400,000

    k_norm_part  <<<NWGP + NBF, 512, 0, stream>>>(x, ei, xq, norm, sn, descG, pairs);
    k_build_gather<<<NB,        256, 0, stream>>>(xq, sn, norm, descG, pairs, beta, out);
}